// Round 1
// baseline (1703.781 us; speedup 1.0000x reference)
//
#include <hip/hip_runtime.h>
#include <hip/hip_bf16.h>

#define N_ENT 64368
#define DIM 128
#define NB 8
#define NREL 40
#define BATCH 64
#define MAXSEED 32

// ---------------------------------------------------------------------------
// seed_mask dtype normalization: harness may hand us bool as int32 (0/1),
// float32 (0.0/1.0), or raw 1-byte bools. Detect from the first 2048 bytes
// (safe to read under every interpretation) and emit int32[2048].
// ---------------------------------------------------------------------------
__global__ void mask_norm_kernel(const unsigned char* __restrict__ raw,
                                 int* __restrict__ outMask) {
    __shared__ int s_ni, s_nf;
    int t = threadIdx.x;
    if (t == 0) { s_ni = 0; s_nf = 0; }
    __syncthreads();
    const unsigned int* u32 = (const unsigned int*)raw;
    int not_int = 0, not_flt = 0;
    for (int i = t; i < 512; i += blockDim.x) {
        unsigned int g = u32[i];
        if (g != 0u && g != 1u) not_int = 1;
        if (g != 0u && g != 0x3F800000u) not_flt = 1;
    }
    if (not_int) atomicOr(&s_ni, 1);
    if (not_flt) atomicOr(&s_nf, 1);
    __syncthreads();
    int mode = (!s_ni) ? 0 : ((!s_nf) ? 1 : 2);  // 0=int32, 1=float32, 2=bytes
    for (int i = t; i < BATCH * MAXSEED; i += blockDim.x) {
        int v;
        if (mode == 0)      v = ((const int*)raw)[i] != 0;
        else if (mode == 1) v = (((const float*)raw)[i] != 0.0f);
        else                v = raw[i] != 0;
        outMask[i] = v;
    }
}

// ---------------------------------------------------------------------------
// Edge aggregation: one wave per edge. Lane l covers float2 at cols 2l,2l+1.
// msg_e = sum_b att[rel_e][b] * basis[b][src_e][:] ; atomically added to agg[dst].
// ---------------------------------------------------------------------------
__global__ __launch_bounds__(256) void edge_kernel(
    const float* __restrict__ basis, const float* __restrict__ att,
    const int* __restrict__ eidx, const int* __restrict__ etype,
    float* __restrict__ agg, int E)
{
    const int lane = threadIdx.x & 63;
    const int wid = blockIdx.x * (blockDim.x >> 6) + (threadIdx.x >> 6);
    const int nw = gridDim.x * (blockDim.x >> 6);
    const int* __restrict__ srcA = eidx;
    const int* __restrict__ dstA = eidx + E;
    for (int e = wid; e < E; e += nw) {
        int s = srcA[e];
        int d = dstA[e];
        int r = etype[e];
        const float* __restrict__ c = att + r * NB;
        float cx[NB];
#pragma unroll
        for (int b = 0; b < NB; ++b) cx[b] = c[b];
        float ax = 0.f, ay = 0.f;
#pragma unroll
        for (int b = 0; b < NB; ++b) {
            const float2 v =
                ((const float2*)(basis + ((size_t)b * N_ENT + s) * DIM))[lane];
            ax += cx[b] * v.x;
            ay += cx[b] * v.y;
        }
        float* dp = agg + (size_t)d * DIM + lane * 2;
        unsafeAtomicAdd(dp, ax);
        unsafeAtomicAdd(dp + 1, ay);
    }
}

// nodes = agg + root + rgcn_bias
__global__ __launch_bounds__(256) void finalize_nodes(
    float* __restrict__ nodes, const float* __restrict__ root,
    const float* __restrict__ bias, int total)
{
    int i = blockIdx.x * blockDim.x + threadIdx.x;
    if (i < total) nodes[i] = nodes[i] + root[i] + bias[i & (DIM - 1)];
}

// ---------------------------------------------------------------------------
// Attention pooling: one block (128 threads) per batch row.
// e_l = sum_d2 tanh(sum_d1 h[l][d1] A[d1][d2]) * bvec[d2]; masked softmax; u = attn^T h
// ---------------------------------------------------------------------------
__global__ __launch_bounds__(128) void attn_kernel(
    const float* __restrict__ nodes, const float* __restrict__ A,
    const float* __restrict__ bvec, const int* __restrict__ seed_idx,
    const int* __restrict__ maskN, float* __restrict__ u)
{
    __shared__ float A_s[DIM * DIM];     // 64 KB
    __shared__ float h_s[MAXSEED * DIM]; // 16 KB
    __shared__ float ev[MAXSEED];
    __shared__ float aw[MAXSEED];
    __shared__ float red[2];
    const int b = blockIdx.x;
    const int t = threadIdx.x;

    for (int i = t; i < DIM * DIM; i += 128) A_s[i] = A[i];
    for (int l = 0; l < MAXSEED; ++l) {
        int idx = seed_idx[b * MAXSEED + l];
        h_s[l * DIM + t] = nodes[(size_t)idx * DIM + t];
    }
    __syncthreads();

    const float bv = bvec[t];
    for (int l = 0; l < MAXSEED; ++l) {
        float s = 0.f;
#pragma unroll 8
        for (int d1 = 0; d1 < DIM; ++d1) s += h_s[l * DIM + d1] * A_s[d1 * DIM + t];
        float val = tanhf(s) * bv;
#pragma unroll
        for (int off = 32; off > 0; off >>= 1) val += __shfl_down(val, off, 64);
        if ((t & 63) == 0) red[t >> 6] = val;
        __syncthreads();
        if (t == 0) ev[l] = red[0] + red[1];
        __syncthreads();
    }

    if (t == 0) {
        float mx = -1e30f;
        for (int l = 0; l < MAXSEED; ++l)
            if (maskN[b * MAXSEED + l]) mx = fmaxf(mx, ev[l]);
        float den = 0.f;
        for (int l = 0; l < MAXSEED; ++l) {
            float w = maskN[b * MAXSEED + l] ? expf(ev[l] - mx) : 0.f;
            aw[l] = w;
            den += w;
        }
        float inv = 1.f / den;
        for (int l = 0; l < MAXSEED; ++l) aw[l] *= inv;
    }
    __syncthreads();

    float s = 0.f;
    for (int l = 0; l < MAXSEED; ++l) s += aw[l] * h_s[l * DIM + t];
    u[b * DIM + t] = s;
}

// ---------------------------------------------------------------------------
// Scores: tile of 64 nodes per block; u (64x128) + node tile (64x129 pad) in LDS.
// ---------------------------------------------------------------------------
__global__ __launch_bounds__(256) void scores_kernel(
    const float* __restrict__ nodes, const float* __restrict__ u,
    const float* __restrict__ obias, float* __restrict__ out)
{
    __shared__ float u_s[BATCH * DIM];   // 32 KB
    __shared__ float n_s[64 * 129];      // 33 KB, +1 pad kills 64-way bank conflict
    const int t = threadIdx.x;
    const int n0 = blockIdx.x * 64;
    for (int i = t; i < BATCH * DIM; i += 256) u_s[i] = u[i];
    for (int i = t; i < 64 * DIM; i += 256) {
        int r = i >> 7, cc = i & 127;
        int n = n0 + r;
        n_s[r * 129 + cc] = (n < N_ENT) ? nodes[(size_t)n * DIM + cc] : 0.f;
    }
    __syncthreads();
    const int nl = t & 63, bg = t >> 6;
    const int n = n0 + nl;
    if (n < N_ENT) {
        const float ob = obias[n];
        const float* __restrict__ nrow = n_s + nl * 129;
        for (int bi = 0; bi < 16; ++bi) {
            int b = bg * 16 + bi;
            const float* __restrict__ ur = u_s + b * DIM;
            float acc = 0.f;
#pragma unroll
            for (int d = 0; d < DIM; ++d) acc += ur[d] * nrow[d];
            out[(size_t)b * N_ENT + n] = acc + ob;
        }
    }
}

// Per-row logsumexp over N_ENT. One block per batch row.
__global__ __launch_bounds__(256) void lse_kernel(
    const float* __restrict__ scores, float* __restrict__ lse)
{
    __shared__ float red[4];
    __shared__ float red2[4];
    const int b = blockIdx.x, t = threadIdx.x;
    const float* __restrict__ row = scores + (size_t)b * N_ENT;
    float mx = -1e30f;
    for (int i = t; i < N_ENT; i += 256) mx = fmaxf(mx, row[i]);
#pragma unroll
    for (int off = 32; off > 0; off >>= 1) mx = fmaxf(mx, __shfl_down(mx, off, 64));
    if ((t & 63) == 0) red[t >> 6] = mx;
    __syncthreads();
    const float m4 = fmaxf(fmaxf(red[0], red[1]), fmaxf(red[2], red[3]));
    float s = 0.f;
    for (int i = t; i < N_ENT; i += 256) s += expf(row[i] - m4);
#pragma unroll
    for (int off = 32; off > 0; off >>= 1) s += __shfl_down(s, off, 64);
    if ((t & 63) == 0) red2[t >> 6] = s;
    __syncthreads();
    if (t == 0) lse[b] = m4 + logf(red2[0] + red2[1] + red2[2] + red2[3]);
}

__global__ void loss_kernel(const float* __restrict__ scores,
                            const float* __restrict__ lse,
                            const int* __restrict__ labels,
                            float* __restrict__ out_loss)
{
    const int t = threadIdx.x;  // 64 threads
    float v = 0.f;
    if (t < BATCH) {
        int lab = labels[t];
        v = lse[t] - scores[(size_t)t * N_ENT + lab];
    }
#pragma unroll
    for (int off = 32; off > 0; off >>= 1) v += __shfl_down(v, off, 64);
    if (t == 0) out_loss[0] = v * (1.0f / BATCH);
}

extern "C" void kernel_launch(void* const* d_in, const int* in_sizes, int n_in,
                              void* d_out, int out_size, void* d_ws, size_t ws_size,
                              hipStream_t stream) {
    const float* basis = (const float*)d_in[0];
    const float* att   = (const float*)d_in[1];
    const float* root  = (const float*)d_in[2];
    const float* rbias = (const float*)d_in[3];
    const float* attnA = (const float*)d_in[4];
    const float* attnB = (const float*)d_in[5];
    const float* obias = (const float*)d_in[6];
    const int* eindex  = (const int*)d_in[7];
    const int* etype   = (const int*)d_in[8];
    const int* sidx    = (const int*)d_in[9];
    const unsigned char* smask = (const unsigned char*)d_in[10];
    const int* labels  = (const int*)d_in[11];
    const int E = in_sizes[8];
    float* out = (float*)d_out;

    // workspace layout
    float* nodes = (float*)d_ws;                      // 64368*128 f32 = 33 MB
    float* u     = nodes + (size_t)N_ENT * DIM;       // 64*128
    float* lse   = u + BATCH * DIM;                   // 64
    int* maskN   = (int*)(lse + BATCH);               // 2048 int32

    hipMemsetAsync(nodes, 0, (size_t)N_ENT * DIM * sizeof(float), stream);
    mask_norm_kernel<<<1, 256, 0, stream>>>(smask, maskN);
    edge_kernel<<<2048, 256, 0, stream>>>(basis, att, eindex, etype, nodes, E);
    finalize_nodes<<<((N_ENT * DIM) + 255) / 256, 256, 0, stream>>>(nodes, root, rbias, N_ENT * DIM);
    attn_kernel<<<BATCH, 128, 0, stream>>>(nodes, attnA, attnB, sidx, maskN, u);
    scores_kernel<<<(N_ENT + 63) / 64, 256, 0, stream>>>(nodes, u, obias, out);
    lse_kernel<<<BATCH, 256, 0, stream>>>(out, lse);
    loss_kernel<<<1, 64, 0, stream>>>(out, lse, labels, out + (size_t)BATCH * N_ENT);
}

// Round 2
// 1382.042 us; speedup vs baseline: 1.2328x; 1.2328x over previous
//
#include <hip/hip_runtime.h>
#include <hip/hip_bf16.h>

#define N_ENT 64368
#define DIM 128
#define NB 8
#define NREL 40
#define BATCH 64
#define MAXSEED 32

// ---------------------------------------------------------------------------
// seed_mask dtype normalization (unchanged from R1 — passed).
// ---------------------------------------------------------------------------
__global__ void mask_norm_kernel(const unsigned char* __restrict__ raw,
                                 int* __restrict__ outMask) {
    __shared__ int s_ni, s_nf;
    int t = threadIdx.x;
    if (t == 0) { s_ni = 0; s_nf = 0; }
    __syncthreads();
    const unsigned int* u32 = (const unsigned int*)raw;
    int not_int = 0, not_flt = 0;
    for (int i = t; i < 512; i += blockDim.x) {
        unsigned int g = u32[i];
        if (g != 0u && g != 1u) not_int = 1;
        if (g != 0u && g != 0x3F800000u) not_flt = 1;
    }
    if (not_int) atomicOr(&s_ni, 1);
    if (not_flt) atomicOr(&s_nf, 1);
    __syncthreads();
    int mode = (!s_ni) ? 0 : ((!s_nf) ? 1 : 2);
    for (int i = t; i < BATCH * MAXSEED; i += blockDim.x) {
        int v;
        if (mode == 0)      v = ((const int*)raw)[i] != 0;
        else if (mode == 1) v = (((const float*)raw)[i] != 0.0f);
        else                v = raw[i] != 0;
        outMask[i] = v;
    }
}

// ---------------------------------------------------------------------------
// Counting-sort infrastructure
// ---------------------------------------------------------------------------
__global__ __launch_bounds__(256) void hist_kernel(
    const int* __restrict__ eidx, int E,
    int* __restrict__ cntS, int* __restrict__ cntD)
{
    int i = blockIdx.x * blockDim.x + threadIdx.x;
    int n = gridDim.x * blockDim.x;
    for (int e = i; e < E; e += n) {
        atomicAdd(&cntS[eidx[e]], 1);
        atomicAdd(&cntD[eidx[e + E]], 1);
    }
}

// Exclusive scan of cnt[N_ENT] -> row_ptr[N_ENT+1] and ofs[N_ENT] (two copies).
// Single block, 1024 threads, 63 values/thread.
__global__ __launch_bounds__(1024) void scan_kernel(
    const int* __restrict__ cnt, int* __restrict__ row_ptr, int* __restrict__ ofs)
{
    __shared__ int s[1024];
    const int t = threadIdx.x;
    const int CH = 63;
    const int base = t * CH;
    int sum = 0;
    for (int j = 0; j < CH; ++j) { int p = base + j; if (p < N_ENT) sum += cnt[p]; }
    s[t] = sum;
    for (int off = 1; off < 1024; off <<= 1) {
        __syncthreads();
        int x = (t >= off) ? s[t - off] : 0;
        __syncthreads();
        s[t] += x;
    }
    __syncthreads();
    int run = s[t] - sum;  // exclusive prefix
    for (int j = 0; j < CH; ++j) {
        int p = base + j;
        if (p < N_ENT) { row_ptr[p] = run; ofs[p] = run; run += cnt[p]; }
    }
    if (t == 1023) row_ptr[N_ENT] = s[1023];
}

// Assign each edge its rank in dst-sorted order.
__global__ __launch_bounds__(256) void rankd_kernel(
    const int* __restrict__ eidx, int E, int* __restrict__ ofsD,
    int* __restrict__ dstpos)
{
    int i = blockIdx.x * blockDim.x + threadIdx.x;
    int n = gridDim.x * blockDim.x;
    for (int e = i; e < E; e += n)
        dstpos[e] = atomicAdd(&ofsD[eidx[e + E]], 1);
}

// Scatter edges into src-sorted order. Payload packs (hi << 6) | rel where
// hi = dstpos (plan A, 21 bits) or dst (plan D fallback, 17 bits).
__global__ __launch_bounds__(256) void scat_kernel(
    const int* __restrict__ eidx, const int* __restrict__ etype, int E,
    int* __restrict__ ofsS, const int* __restrict__ dstpos,
    unsigned* __restrict__ srcSorted)
{
    int i = blockIdx.x * blockDim.x + threadIdx.x;
    int n = gridDim.x * blockDim.x;
    for (int e = i; e < E; e += n) {
        int s = eidx[e];
        int p = atomicAdd(&ofsS[s], 1);
        unsigned hi = dstpos ? (unsigned)dstpos[e] : (unsigned)eidx[e + E];
        srcSorted[p] = (hi << 6) | (unsigned)etype[e];
    }
}

// ---------------------------------------------------------------------------
// Plan A: per-src register-cached basis, messages written to dst-sorted slots.
// One wave per src (grid*4 == N_ENT exactly).
// ---------------------------------------------------------------------------
__global__ __launch_bounds__(256) void msg_kernel(
    const float* __restrict__ basis, const float* __restrict__ att,
    const int* __restrict__ row_ptrS, const unsigned* __restrict__ srcSorted,
    float* __restrict__ msg)
{
    __shared__ float att_s[NREL * NB];
    const int t = threadIdx.x;
    if (t < NREL * NB) att_s[t] = att[t];
    __syncthreads();
    const int lane = t & 63;
    const int s = blockIdx.x * 4 + (t >> 6);
    const int r0 = row_ptrS[s], r1 = row_ptrS[s + 1];
    if (r0 == r1) return;
    float2 B[NB];
#pragma unroll
    for (int b = 0; b < NB; ++b)
        B[b] = ((const float2*)(basis + ((size_t)b * N_ENT + s) * DIM))[lane];
    for (int i = r0; i < r1; ++i) {
        unsigned pk = srcSorted[i];
        const float* __restrict__ c = att_s + (pk & 63u) * NB;
        size_t dp = (size_t)(pk >> 6);
        float mx = 0.f, my = 0.f;
#pragma unroll
        for (int b = 0; b < NB; ++b) { mx += c[b] * B[b].x; my += c[b] * B[b].y; }
        union { float2 f; unsigned long long u; } v;
        v.f = make_float2(mx, my);
        __builtin_nontemporal_store(v.u,
            (unsigned long long*)(msg + dp * DIM) + lane);
    }
}

// Segmented reduce over dst-sorted messages; writes nodes once (fused root+bias).
__global__ __launch_bounds__(256) void reduce_kernel(
    const float* __restrict__ msg, const int* __restrict__ row_ptrD,
    const float* __restrict__ root, const float* __restrict__ rbias,
    float* __restrict__ nodes)
{
    const int t = threadIdx.x;
    const int lane = t & 63;
    const int d = blockIdx.x * 4 + (t >> 6);
    const int r0 = row_ptrD[d], r1 = row_ptrD[d + 1];
    float2 acc = ((const float2*)(root + (size_t)d * DIM))[lane];
    acc.x += rbias[lane * 2];
    acc.y += rbias[lane * 2 + 1];
    for (int i = r0; i < r1; ++i) {
        unsigned long long u = __builtin_nontemporal_load(
            (const unsigned long long*)(msg + (size_t)i * DIM) + lane);
        union { unsigned long long u; float2 f; } v; v.u = u;
        acc.x += v.f.x; acc.y += v.f.y;
    }
    ((float2*)(nodes + (size_t)d * DIM))[lane] = acc;
}

// ---------------------------------------------------------------------------
// Plan D fallback (small ws): src-sorted + register basis + fp32 atomics.
// ---------------------------------------------------------------------------
__global__ __launch_bounds__(256) void edge_atomic_kernel(
    const float* __restrict__ basis, const float* __restrict__ att,
    const int* __restrict__ row_ptrS, const unsigned* __restrict__ srcSorted,
    float* __restrict__ nodes)
{
    __shared__ float att_s[NREL * NB];
    const int t = threadIdx.x;
    if (t < NREL * NB) att_s[t] = att[t];
    __syncthreads();
    const int lane = t & 63;
    const int s = blockIdx.x * 4 + (t >> 6);
    const int r0 = row_ptrS[s], r1 = row_ptrS[s + 1];
    if (r0 == r1) return;
    float2 B[NB];
#pragma unroll
    for (int b = 0; b < NB; ++b)
        B[b] = ((const float2*)(basis + ((size_t)b * N_ENT + s) * DIM))[lane];
    for (int i = r0; i < r1; ++i) {
        unsigned pk = srcSorted[i];
        const float* __restrict__ c = att_s + (pk & 63u) * NB;
        int d = (int)(pk >> 6);
        float mx = 0.f, my = 0.f;
#pragma unroll
        for (int b = 0; b < NB; ++b) { mx += c[b] * B[b].x; my += c[b] * B[b].y; }
        float* dp = nodes + (size_t)d * DIM + lane * 2;
        unsafeAtomicAdd(dp, mx);
        unsafeAtomicAdd(dp + 1, my);
    }
}

__global__ __launch_bounds__(256) void finalize_nodes(
    float* __restrict__ nodes, const float* __restrict__ root,
    const float* __restrict__ bias, int total)
{
    int i = blockIdx.x * blockDim.x + threadIdx.x;
    if (i < total) nodes[i] = nodes[i] + root[i] + bias[i & (DIM - 1)];
}

// ---------------------------------------------------------------------------
// Attention pooling (unchanged from R1 — passed).
// ---------------------------------------------------------------------------
__global__ __launch_bounds__(128) void attn_kernel(
    const float* __restrict__ nodes, const float* __restrict__ A,
    const float* __restrict__ bvec, const int* __restrict__ seed_idx,
    const int* __restrict__ maskN, float* __restrict__ u)
{
    __shared__ float A_s[DIM * DIM];
    __shared__ float h_s[MAXSEED * DIM];
    __shared__ float ev[MAXSEED];
    __shared__ float aw[MAXSEED];
    __shared__ float red[2];
    const int b = blockIdx.x;
    const int t = threadIdx.x;

    for (int i = t; i < DIM * DIM; i += 128) A_s[i] = A[i];
    for (int l = 0; l < MAXSEED; ++l) {
        int idx = seed_idx[b * MAXSEED + l];
        h_s[l * DIM + t] = nodes[(size_t)idx * DIM + t];
    }
    __syncthreads();

    const float bv = bvec[t];
    for (int l = 0; l < MAXSEED; ++l) {
        float s = 0.f;
#pragma unroll 8
        for (int d1 = 0; d1 < DIM; ++d1) s += h_s[l * DIM + d1] * A_s[d1 * DIM + t];
        float val = tanhf(s) * bv;
#pragma unroll
        for (int off = 32; off > 0; off >>= 1) val += __shfl_down(val, off, 64);
        if ((t & 63) == 0) red[t >> 6] = val;
        __syncthreads();
        if (t == 0) ev[l] = red[0] + red[1];
        __syncthreads();
    }

    if (t == 0) {
        float mx = -1e30f;
        for (int l = 0; l < MAXSEED; ++l)
            if (maskN[b * MAXSEED + l]) mx = fmaxf(mx, ev[l]);
        float den = 0.f;
        for (int l = 0; l < MAXSEED; ++l) {
            float w = maskN[b * MAXSEED + l] ? expf(ev[l] - mx) : 0.f;
            aw[l] = w;
            den += w;
        }
        float inv = 1.f / den;
        for (int l = 0; l < MAXSEED; ++l) aw[l] *= inv;
    }
    __syncthreads();

    float s = 0.f;
    for (int l = 0; l < MAXSEED; ++l) s += aw[l] * h_s[l * DIM + t];
    u[b * DIM + t] = s;
}

// ---------------------------------------------------------------------------
// Scores (unchanged from R1 — passed).
// ---------------------------------------------------------------------------
__global__ __launch_bounds__(256) void scores_kernel(
    const float* __restrict__ nodes, const float* __restrict__ u,
    const float* __restrict__ obias, float* __restrict__ out)
{
    __shared__ float u_s[BATCH * DIM];
    __shared__ float n_s[64 * 129];
    const int t = threadIdx.x;
    const int n0 = blockIdx.x * 64;
    for (int i = t; i < BATCH * DIM; i += 256) u_s[i] = u[i];
    for (int i = t; i < 64 * DIM; i += 256) {
        int r = i >> 7, cc = i & 127;
        int n = n0 + r;
        n_s[r * 129 + cc] = (n < N_ENT) ? nodes[(size_t)n * DIM + cc] : 0.f;
    }
    __syncthreads();
    const int nl = t & 63, bg = t >> 6;
    const int n = n0 + nl;
    if (n < N_ENT) {
        const float ob = obias[n];
        const float* __restrict__ nrow = n_s + nl * 129;
        for (int bi = 0; bi < 16; ++bi) {
            int b = bg * 16 + bi;
            const float* __restrict__ ur = u_s + b * DIM;
            float acc = 0.f;
#pragma unroll
            for (int d = 0; d < DIM; ++d) acc += ur[d] * nrow[d];
            out[(size_t)b * N_ENT + n] = acc + ob;
        }
    }
}

// ---------------------------------------------------------------------------
// Two-stage logsumexp: 8 chunks per row (512 blocks), then combine.
// ---------------------------------------------------------------------------
#define LSE_CH 8
__global__ __launch_bounds__(256) void lse1_kernel(
    const float* __restrict__ scores, float2* __restrict__ pls)
{
    const int b = blockIdx.x >> 3, c = blockIdx.x & 7;
    const int t = threadIdx.x;
    const int CH = (N_ENT + LSE_CH - 1) / LSE_CH;
    const int i0 = c * CH, i1 = min(N_ENT, i0 + CH);
    const float* __restrict__ row = scores + (size_t)b * N_ENT;
    __shared__ float red[4], red2[4];
    float mx = -1e30f;
    for (int i = i0 + t; i < i1; i += 256) mx = fmaxf(mx, row[i]);
#pragma unroll
    for (int off = 32; off > 0; off >>= 1) mx = fmaxf(mx, __shfl_down(mx, off, 64));
    if ((t & 63) == 0) red[t >> 6] = mx;
    __syncthreads();
    const float m4 = fmaxf(fmaxf(red[0], red[1]), fmaxf(red[2], red[3]));
    float ss = 0.f;
    for (int i = i0 + t; i < i1; i += 256) ss += expf(row[i] - m4);
#pragma unroll
    for (int off = 32; off > 0; off >>= 1) ss += __shfl_down(ss, off, 64);
    if ((t & 63) == 0) red2[t >> 6] = ss;
    __syncthreads();
    if (t == 0) pls[blockIdx.x] = make_float2(m4, red2[0] + red2[1] + red2[2] + red2[3]);
}

__global__ void lse2_kernel(const float2* __restrict__ pls, float* __restrict__ lse)
{
    const int b = threadIdx.x;
    if (b < BATCH) {
        float M = -1e30f;
        for (int c = 0; c < LSE_CH; ++c) M = fmaxf(M, pls[b * LSE_CH + c].x);
        float S = 0.f;
        for (int c = 0; c < LSE_CH; ++c) {
            float2 p = pls[b * LSE_CH + c];
            S += p.y * expf(p.x - M);
        }
        lse[b] = M + logf(S);
    }
}

__global__ void loss_kernel(const float* __restrict__ scores,
                            const float* __restrict__ lse,
                            const int* __restrict__ labels,
                            float* __restrict__ out_loss)
{
    const int t = threadIdx.x;
    float v = 0.f;
    if (t < BATCH) {
        int lab = labels[t];
        v = lse[t] - scores[(size_t)t * N_ENT + lab];
    }
#pragma unroll
    for (int off = 32; off > 0; off >>= 1) v += __shfl_down(v, off, 64);
    if (t == 0) out_loss[0] = v * (1.0f / BATCH);
}

extern "C" void kernel_launch(void* const* d_in, const int* in_sizes, int n_in,
                              void* d_out, int out_size, void* d_ws, size_t ws_size,
                              hipStream_t stream) {
    const float* basis = (const float*)d_in[0];
    const float* att   = (const float*)d_in[1];
    const float* root  = (const float*)d_in[2];
    const float* rbias = (const float*)d_in[3];
    const float* attnA = (const float*)d_in[4];
    const float* attnB = (const float*)d_in[5];
    const float* obias = (const float*)d_in[6];
    const int* eindex  = (const int*)d_in[7];
    const int* etype   = (const int*)d_in[8];
    const int* sidx    = (const int*)d_in[9];
    const unsigned char* smask = (const unsigned char*)d_in[10];
    const int* labels  = (const int*)d_in[11];
    const int E = in_sizes[8];
    float* out = (float*)d_out;

    // ---- workspace layout ----
    auto alignup = [](size_t x) { return (x + 511) & ~(size_t)511; };
    char* p = (char*)d_ws;
    float* nodes = (float*)p;      p += alignup((size_t)N_ENT * DIM * 4);
    float* u     = (float*)p;      p += alignup((size_t)BATCH * DIM * 4);
    float* lse   = (float*)p;      p += alignup(BATCH * 4);
    float2* pls  = (float2*)p;     p += alignup(BATCH * LSE_CH * 8);
    int* maskN   = (int*)p;        p += alignup(BATCH * MAXSEED * 4);
    int* cntS    = (int*)p;        // cntS and cntD contiguous: one memset
    int* cntD    = cntS + N_ENT;   p += alignup((size_t)2 * N_ENT * 4);
    int* row_ptrS= (int*)p;        p += alignup((size_t)(N_ENT + 1) * 4);
    int* ofsS    = (int*)p;        p += alignup((size_t)N_ENT * 4);
    int* row_ptrD= (int*)p;        p += alignup((size_t)(N_ENT + 1) * 4);
    int* ofsD    = (int*)p;        p += alignup((size_t)N_ENT * 4);
    int* dstpos  = (int*)p;        p += alignup((size_t)E * 4);
    unsigned* srcSorted = (unsigned*)p; p += alignup((size_t)E * 4);
    float* msg   = (float*)p;      p += alignup((size_t)E * DIM * 4);
    const bool planA = ((size_t)(p - (char*)d_ws) <= ws_size);

    const int eb = (E + 255) / 256;
    const int egrid = eb > 4096 ? 4096 : eb;

    mask_norm_kernel<<<1, 256, 0, stream>>>(smask, maskN);
    hipMemsetAsync(cntS, 0, (size_t)2 * N_ENT * 4, stream);
    hist_kernel<<<egrid, 256, 0, stream>>>(eindex, E, cntS, cntD);
    scan_kernel<<<1, 1024, 0, stream>>>(cntS, row_ptrS, ofsS);

    if (planA) {
        scan_kernel<<<1, 1024, 0, stream>>>(cntD, row_ptrD, ofsD);
        rankd_kernel<<<egrid, 256, 0, stream>>>(eindex, E, ofsD, dstpos);
        scat_kernel<<<egrid, 256, 0, stream>>>(eindex, etype, E, ofsS, dstpos, srcSorted);
        msg_kernel<<<N_ENT / 4, 256, 0, stream>>>(basis, att, row_ptrS, srcSorted, msg);
        reduce_kernel<<<N_ENT / 4, 256, 0, stream>>>(msg, row_ptrD, root, rbias, nodes);
    } else {
        hipMemsetAsync(nodes, 0, (size_t)N_ENT * DIM * 4, stream);
        scat_kernel<<<egrid, 256, 0, stream>>>(eindex, etype, E, ofsS, (const int*)nullptr, srcSorted);
        edge_atomic_kernel<<<N_ENT / 4, 256, 0, stream>>>(basis, att, row_ptrS, srcSorted, nodes);
        finalize_nodes<<<((N_ENT * DIM) + 255) / 256, 256, 0, stream>>>(nodes, root, rbias, N_ENT * DIM);
    }

    attn_kernel<<<BATCH, 128, 0, stream>>>(nodes, attnA, attnB, sidx, maskN, u);
    scores_kernel<<<(N_ENT + 63) / 64, 256, 0, stream>>>(nodes, u, obias, out);
    lse1_kernel<<<BATCH * LSE_CH, 256, 0, stream>>>(out, pls);
    lse2_kernel<<<1, 64, 0, stream>>>(pls, lse);
    loss_kernel<<<1, 64, 0, stream>>>(out, lse, labels, out + (size_t)BATCH * N_ENT);
}

// Round 3
// 1114.041 us; speedup vs baseline: 1.5294x; 1.2406x over previous
//
#include <hip/hip_runtime.h>
#include <hip/hip_bf16.h>

#define N_ENT 64368
#define DIM 128
#define NB 8
#define NREL 40
#define BATCH 64
#define MAXSEED 32

// ---------------------------------------------------------------------------
// bf16 pack/unpack helpers (RNE)
// ---------------------------------------------------------------------------
__device__ __forceinline__ unsigned pack_bf2(float x, float y) {
    union { float f; unsigned u; } a, b;
    a.f = x; b.f = y;
    unsigned ra = a.u + 0x7FFFu + ((a.u >> 16) & 1u);
    unsigned rb = b.u + 0x7FFFu + ((b.u >> 16) & 1u);
    return (ra >> 16) | (rb & 0xFFFF0000u);
}

// ---------------------------------------------------------------------------
// seed_mask dtype normalization (unchanged — verified R1/R2).
// ---------------------------------------------------------------------------
__global__ void mask_norm_kernel(const unsigned char* __restrict__ raw,
                                 int* __restrict__ outMask) {
    __shared__ int s_ni, s_nf;
    int t = threadIdx.x;
    if (t == 0) { s_ni = 0; s_nf = 0; }
    __syncthreads();
    const unsigned int* u32 = (const unsigned int*)raw;
    int not_int = 0, not_flt = 0;
    for (int i = t; i < 512; i += blockDim.x) {
        unsigned int g = u32[i];
        if (g != 0u && g != 1u) not_int = 1;
        if (g != 0u && g != 0x3F800000u) not_flt = 1;
    }
    if (not_int) atomicOr(&s_ni, 1);
    if (not_flt) atomicOr(&s_nf, 1);
    __syncthreads();
    int mode = (!s_ni) ? 0 : ((!s_nf) ? 1 : 2);
    for (int i = t; i < BATCH * MAXSEED; i += blockDim.x) {
        int v;
        if (mode == 0)      v = ((const int*)raw)[i] != 0;
        else if (mode == 1) v = (((const float*)raw)[i] != 0.0f);
        else                v = raw[i] != 0;
        outMask[i] = v;
    }
}

// ---------------------------------------------------------------------------
// Counting-sort infrastructure
// ---------------------------------------------------------------------------
__global__ __launch_bounds__(256) void hist_kernel(
    const int* __restrict__ eidx, int E,
    int* __restrict__ cntS, int* __restrict__ cntD)
{
    int i = blockIdx.x * blockDim.x + threadIdx.x;
    int n = gridDim.x * blockDim.x;
    for (int e = i; e < E; e += n) {
        atomicAdd(&cntS[eidx[e]], 1);
        atomicAdd(&cntD[eidx[e + E]], 1);
    }
}

// Exclusive scan of cnt[N_ENT] -> row_ptr[N_ENT+1] and ofs[N_ENT].
// blockIdx 0 scans the src histogram, blockIdx 1 the dst histogram.
__global__ __launch_bounds__(1024) void scan2_kernel(
    const int* __restrict__ cntS, int* __restrict__ rpS, int* __restrict__ ofS,
    const int* __restrict__ cntD, int* __restrict__ rpD, int* __restrict__ ofD)
{
    const int* cnt = blockIdx.x ? cntD : cntS;
    int* row_ptr   = blockIdx.x ? rpD : rpS;
    int* ofs       = blockIdx.x ? ofD : ofS;
    __shared__ int s[1024];
    const int t = threadIdx.x;
    const int CH = 63;
    const int base = t * CH;
    int sum = 0;
    for (int j = 0; j < CH; ++j) { int p = base + j; if (p < N_ENT) sum += cnt[p]; }
    s[t] = sum;
    for (int off = 1; off < 1024; off <<= 1) {
        __syncthreads();
        int x = (t >= off) ? s[t - off] : 0;
        __syncthreads();
        s[t] += x;
    }
    __syncthreads();
    int run = s[t] - sum;
    for (int j = 0; j < CH; ++j) {
        int p = base + j;
        if (p < N_ENT) { row_ptr[p] = run; ofs[p] = run; run += cnt[p]; }
    }
    if (t == 1023) row_ptr[N_ENT] = s[1023];
}

// Fused ranking + scatter: one O(E) pass. For each edge, grab its slot in
// src-order (p) and its rank in dst-order (dp); payload = (dp<<6)|rel.
// useDstId: plan-D fallback packs raw dst id instead of dst rank.
__global__ __launch_bounds__(256) void scat2_kernel(
    const int* __restrict__ eidx, const int* __restrict__ etype, int E,
    int* __restrict__ ofsS, int* __restrict__ ofsD, int useDstRank,
    unsigned* __restrict__ srcSorted)
{
    int i = blockIdx.x * blockDim.x + threadIdx.x;
    int n = gridDim.x * blockDim.x;
    for (int e = i; e < E; e += n) {
        int s = eidx[e];
        int d = eidx[e + E];
        int p = atomicAdd(&ofsS[s], 1);
        unsigned hi = useDstRank ? (unsigned)atomicAdd(&ofsD[d], 1) : (unsigned)d;
        srcSorted[p] = (hi << 6) | (unsigned)etype[e];
    }
}

// ---------------------------------------------------------------------------
// Plan A msg: per-src register-cached basis; bf16x2-packed messages written
// non-temporally to dst-sorted slots (256 B per edge). One wave per src.
// ---------------------------------------------------------------------------
__global__ __launch_bounds__(256) void msg_kernel(
    const float* __restrict__ basis, const float* __restrict__ att,
    const int* __restrict__ row_ptrS, const unsigned* __restrict__ srcSorted,
    unsigned* __restrict__ msg)
{
    __shared__ float att_s[NREL * NB];
    const int t = threadIdx.x;
    for (int i = t; i < NREL * NB; i += 256) att_s[i] = att[i];  // R2 bug fix: 320 > 256
    __syncthreads();
    const int lane = t & 63;
    const int s = blockIdx.x * 4 + (t >> 6);
    const int r0 = row_ptrS[s], r1 = row_ptrS[s + 1];
    if (r0 == r1) return;
    float2 B[NB];
#pragma unroll
    for (int b = 0; b < NB; ++b)
        B[b] = ((const float2*)(basis + ((size_t)b * N_ENT + s) * DIM))[lane];
    for (int i = r0; i < r1; ++i) {
        unsigned pk = srcSorted[i];
        const float* __restrict__ c = att_s + (pk & 63u) * NB;
        size_t dp = (size_t)(pk >> 6);
        float mx = 0.f, my = 0.f;
#pragma unroll
        for (int b = 0; b < NB; ++b) { mx += c[b] * B[b].x; my += c[b] * B[b].y; }
        __builtin_nontemporal_store(pack_bf2(mx, my), msg + dp * 64 + lane);
    }
}

// Segmented reduce over dst-sorted bf16 messages; writes nodes once (+root+bias).
__global__ __launch_bounds__(256) void reduce_kernel(
    const unsigned* __restrict__ msg, const int* __restrict__ row_ptrD,
    const float* __restrict__ root, const float* __restrict__ rbias,
    float* __restrict__ nodes)
{
    const int t = threadIdx.x;
    const int lane = t & 63;
    const int d = blockIdx.x * 4 + (t >> 6);
    const int r0 = row_ptrD[d], r1 = row_ptrD[d + 1];
    float2 acc = ((const float2*)(root + (size_t)d * DIM))[lane];
    acc.x += rbias[lane * 2];
    acc.y += rbias[lane * 2 + 1];
    for (int i = r0; i < r1; ++i) {
        unsigned u = __builtin_nontemporal_load(msg + (size_t)i * 64 + lane);
        acc.x += __uint_as_float(u << 16);
        acc.y += __uint_as_float(u & 0xFFFF0000u);
    }
    ((float2*)(nodes + (size_t)d * DIM))[lane] = acc;
}

// ---------------------------------------------------------------------------
// Plan D fallback (small ws): src-sorted + register basis + fp32 atomics.
// ---------------------------------------------------------------------------
__global__ __launch_bounds__(256) void edge_atomic_kernel(
    const float* __restrict__ basis, const float* __restrict__ att,
    const int* __restrict__ row_ptrS, const unsigned* __restrict__ srcSorted,
    float* __restrict__ nodes)
{
    __shared__ float att_s[NREL * NB];
    const int t = threadIdx.x;
    for (int i = t; i < NREL * NB; i += 256) att_s[i] = att[i];
    __syncthreads();
    const int lane = t & 63;
    const int s = blockIdx.x * 4 + (t >> 6);
    const int r0 = row_ptrS[s], r1 = row_ptrS[s + 1];
    if (r0 == r1) return;
    float2 B[NB];
#pragma unroll
    for (int b = 0; b < NB; ++b)
        B[b] = ((const float2*)(basis + ((size_t)b * N_ENT + s) * DIM))[lane];
    for (int i = r0; i < r1; ++i) {
        unsigned pk = srcSorted[i];
        const float* __restrict__ c = att_s + (pk & 63u) * NB;
        int d = (int)(pk >> 6);
        float mx = 0.f, my = 0.f;
#pragma unroll
        for (int b = 0; b < NB; ++b) { mx += c[b] * B[b].x; my += c[b] * B[b].y; }
        float* dp = nodes + (size_t)d * DIM + lane * 2;
        unsafeAtomicAdd(dp, mx);
        unsafeAtomicAdd(dp + 1, my);
    }
}

__global__ __launch_bounds__(256) void finalize_nodes(
    float* __restrict__ nodes, const float* __restrict__ root,
    const float* __restrict__ bias, int total)
{
    int i = blockIdx.x * blockDim.x + threadIdx.x;
    if (i < total) nodes[i] = nodes[i] + root[i] + bias[i & (DIM - 1)];
}

// ---------------------------------------------------------------------------
// Attention pooling (unchanged — verified R1/R2).
// ---------------------------------------------------------------------------
__global__ __launch_bounds__(128) void attn_kernel(
    const float* __restrict__ nodes, const float* __restrict__ A,
    const float* __restrict__ bvec, const int* __restrict__ seed_idx,
    const int* __restrict__ maskN, float* __restrict__ u)
{
    __shared__ float A_s[DIM * DIM];
    __shared__ float h_s[MAXSEED * DIM];
    __shared__ float ev[MAXSEED];
    __shared__ float aw[MAXSEED];
    __shared__ float red[2];
    const int b = blockIdx.x;
    const int t = threadIdx.x;

    for (int i = t; i < DIM * DIM; i += 128) A_s[i] = A[i];
    for (int l = 0; l < MAXSEED; ++l) {
        int idx = seed_idx[b * MAXSEED + l];
        h_s[l * DIM + t] = nodes[(size_t)idx * DIM + t];
    }
    __syncthreads();

    const float bv = bvec[t];
    for (int l = 0; l < MAXSEED; ++l) {
        float s = 0.f;
#pragma unroll 8
        for (int d1 = 0; d1 < DIM; ++d1) s += h_s[l * DIM + d1] * A_s[d1 * DIM + t];
        float val = tanhf(s) * bv;
#pragma unroll
        for (int off = 32; off > 0; off >>= 1) val += __shfl_down(val, off, 64);
        if ((t & 63) == 0) red[t >> 6] = val;
        __syncthreads();
        if (t == 0) ev[l] = red[0] + red[1];
        __syncthreads();
    }

    if (t == 0) {
        float mx = -1e30f;
        for (int l = 0; l < MAXSEED; ++l)
            if (maskN[b * MAXSEED + l]) mx = fmaxf(mx, ev[l]);
        float den = 0.f;
        for (int l = 0; l < MAXSEED; ++l) {
            float w = maskN[b * MAXSEED + l] ? expf(ev[l] - mx) : 0.f;
            aw[l] = w;
            den += w;
        }
        float inv = 1.f / den;
        for (int l = 0; l < MAXSEED; ++l) aw[l] *= inv;
    }
    __syncthreads();

    float s = 0.f;
    for (int l = 0; l < MAXSEED; ++l) s += aw[l] * h_s[l * DIM + t];
    u[b * DIM + t] = s;
}

// ---------------------------------------------------------------------------
// Scores, register-accumulator version: lane nl streams node row n0+nl from
// global (L2-resident, 4x reuse), u tile via wave-uniform LDS broadcasts,
// acc[16] in VGPRs. Old version moved ~1 MB of LDS per wave; this ~40 KB.
// ---------------------------------------------------------------------------
__global__ __launch_bounds__(256) void scores_kernel(
    const float* __restrict__ nodes, const float* __restrict__ u,
    const float* __restrict__ obias, float* __restrict__ out)
{
    __shared__ float u_s[BATCH * DIM];   // 32 KB
    const int t = threadIdx.x;
    const int n0 = blockIdx.x * 64;
    for (int i = t; i < BATCH * DIM; i += 256) u_s[i] = u[i];
    __syncthreads();
    const int nl = t & 63, bg = t >> 6;
    const int n = n0 + nl;
    const int nc = n < N_ENT ? n : N_ENT - 1;
    const float4* __restrict__ nrow = (const float4*)(nodes + (size_t)nc * DIM);
    float acc[16];
#pragma unroll
    for (int bi = 0; bi < 16; ++bi) acc[bi] = 0.f;
    for (int dc = 0; dc < DIM / 4; ++dc) {
        const float4 nr = nrow[dc];
#pragma unroll
        for (int bi = 0; bi < 16; ++bi) {
            const float4 uu = *(const float4*)(u_s + (bg * 16 + bi) * DIM + dc * 4);
            acc[bi] += nr.x * uu.x + nr.y * uu.y + nr.z * uu.z + nr.w * uu.w;
        }
    }
    if (n < N_ENT) {
        const float ob = obias[n];
#pragma unroll
        for (int bi = 0; bi < 16; ++bi)
            out[(size_t)(bg * 16 + bi) * N_ENT + n] = acc[bi] + ob;
    }
}

// ---------------------------------------------------------------------------
// Two-stage logsumexp: 8 chunks per row (512 blocks), then combine.
// ---------------------------------------------------------------------------
#define LSE_CH 8
__global__ __launch_bounds__(256) void lse1_kernel(
    const float* __restrict__ scores, float2* __restrict__ pls)
{
    const int b = blockIdx.x >> 3, c = blockIdx.x & 7;
    const int t = threadIdx.x;
    const int CH = (N_ENT + LSE_CH - 1) / LSE_CH;
    const int i0 = c * CH, i1 = min(N_ENT, i0 + CH);
    const float* __restrict__ row = scores + (size_t)b * N_ENT;
    __shared__ float red[4], red2[4];
    float mx = -1e30f;
    for (int i = i0 + t; i < i1; i += 256) mx = fmaxf(mx, row[i]);
#pragma unroll
    for (int off = 32; off > 0; off >>= 1) mx = fmaxf(mx, __shfl_down(mx, off, 64));
    if ((t & 63) == 0) red[t >> 6] = mx;
    __syncthreads();
    const float m4 = fmaxf(fmaxf(red[0], red[1]), fmaxf(red[2], red[3]));
    float ss = 0.f;
    for (int i = i0 + t; i < i1; i += 256) ss += expf(row[i] - m4);
#pragma unroll
    for (int off = 32; off > 0; off >>= 1) ss += __shfl_down(ss, off, 64);
    if ((t & 63) == 0) red2[t >> 6] = ss;
    __syncthreads();
    if (t == 0) pls[blockIdx.x] = make_float2(m4, red2[0] + red2[1] + red2[2] + red2[3]);
}

__global__ void lse2_kernel(const float2* __restrict__ pls, float* __restrict__ lse)
{
    const int b = threadIdx.x;
    if (b < BATCH) {
        float M = -1e30f;
        for (int c = 0; c < LSE_CH; ++c) M = fmaxf(M, pls[b * LSE_CH + c].x);
        float S = 0.f;
        for (int c = 0; c < LSE_CH; ++c) {
            float2 p = pls[b * LSE_CH + c];
            S += p.y * expf(p.x - M);
        }
        lse[b] = M + logf(S);
    }
}

__global__ void loss_kernel(const float* __restrict__ scores,
                            const float* __restrict__ lse,
                            const int* __restrict__ labels,
                            float* __restrict__ out_loss)
{
    const int t = threadIdx.x;
    float v = 0.f;
    if (t < BATCH) {
        int lab = labels[t];
        v = lse[t] - scores[(size_t)t * N_ENT + lab];
    }
#pragma unroll
    for (int off = 32; off > 0; off >>= 1) v += __shfl_down(v, off, 64);
    if (t == 0) out_loss[0] = v * (1.0f / BATCH);
}

extern "C" void kernel_launch(void* const* d_in, const int* in_sizes, int n_in,
                              void* d_out, int out_size, void* d_ws, size_t ws_size,
                              hipStream_t stream) {
    const float* basis = (const float*)d_in[0];
    const float* att   = (const float*)d_in[1];
    const float* root  = (const float*)d_in[2];
    const float* rbias = (const float*)d_in[3];
    const float* attnA = (const float*)d_in[4];
    const float* attnB = (const float*)d_in[5];
    const float* obias = (const float*)d_in[6];
    const int* eindex  = (const int*)d_in[7];
    const int* etype   = (const int*)d_in[8];
    const int* sidx    = (const int*)d_in[9];
    const unsigned char* smask = (const unsigned char*)d_in[10];
    const int* labels  = (const int*)d_in[11];
    const int E = in_sizes[8];
    float* out = (float*)d_out;

    // ---- workspace layout ----
    auto alignup = [](size_t x) { return (x + 511) & ~(size_t)511; };
    char* p = (char*)d_ws;
    float* nodes = (float*)p;      p += alignup((size_t)N_ENT * DIM * 4);
    float* u     = (float*)p;      p += alignup((size_t)BATCH * DIM * 4);
    float* lse   = (float*)p;      p += alignup(BATCH * 4);
    float2* pls  = (float2*)p;     p += alignup(BATCH * LSE_CH * 8);
    int* maskN   = (int*)p;        p += alignup(BATCH * MAXSEED * 4);
    int* cntS    = (int*)p;
    int* cntD    = cntS + N_ENT;   p += alignup((size_t)2 * N_ENT * 4);
    int* row_ptrS= (int*)p;        p += alignup((size_t)(N_ENT + 1) * 4);
    int* ofsS    = (int*)p;        p += alignup((size_t)N_ENT * 4);
    int* row_ptrD= (int*)p;        p += alignup((size_t)(N_ENT + 1) * 4);
    int* ofsD    = (int*)p;        p += alignup((size_t)N_ENT * 4);
    unsigned* srcSorted = (unsigned*)p; p += alignup((size_t)E * 4);
    unsigned* msg = (unsigned*)p;  p += alignup((size_t)E * 64 * 4);  // bf16x2 per lane
    const bool planA = ((size_t)(p - (char*)d_ws) <= ws_size);

    const int eb = (E + 255) / 256;
    const int egrid = eb > 2048 ? 2048 : eb;

    mask_norm_kernel<<<1, 256, 0, stream>>>(smask, maskN);
    hipMemsetAsync(cntS, 0, (size_t)2 * N_ENT * 4, stream);
    hist_kernel<<<egrid, 256, 0, stream>>>(eindex, E, cntS, cntD);
    scan2_kernel<<<2, 1024, 0, stream>>>(cntS, row_ptrS, ofsS, cntD, row_ptrD, ofsD);

    if (planA) {
        scat2_kernel<<<egrid, 256, 0, stream>>>(eindex, etype, E, ofsS, ofsD, 1, srcSorted);
        msg_kernel<<<N_ENT / 4, 256, 0, stream>>>(basis, att, row_ptrS, srcSorted, msg);
        reduce_kernel<<<N_ENT / 4, 256, 0, stream>>>(msg, row_ptrD, root, rbias, nodes);
    } else {
        hipMemsetAsync(nodes, 0, (size_t)N_ENT * DIM * 4, stream);
        scat2_kernel<<<egrid, 256, 0, stream>>>(eindex, etype, E, ofsS, ofsD, 0, srcSorted);
        edge_atomic_kernel<<<N_ENT / 4, 256, 0, stream>>>(basis, att, row_ptrS, srcSorted, nodes);
        finalize_nodes<<<((N_ENT * DIM) + 255) / 256, 256, 0, stream>>>(nodes, root, rbias, N_ENT * DIM);
    }

    attn_kernel<<<BATCH, 128, 0, stream>>>(nodes, attnA, attnB, sidx, maskN, u);
    scores_kernel<<<(N_ENT + 63) / 64, 256, 0, stream>>>(nodes, u, obias, out);
    lse1_kernel<<<BATCH * LSE_CH, 256, 0, stream>>>(out, pls);
    lse2_kernel<<<1, 64, 0, stream>>>(pls, lse);
    loss_kernel<<<1, 64, 0, stream>>>(out, lse, labels, out + (size_t)BATCH * N_ENT);
}

// Round 4
// 1040.764 us; speedup vs baseline: 1.6370x; 1.0704x over previous
//
#include <hip/hip_runtime.h>
#include <hip/hip_bf16.h>

#define N_ENT 64368
#define DIM 128
#define NB 8
#define NREL 40
#define BATCH 64
#define MAXSEED 32
#define OPAD 16   // ints per padded atomic counter = 64 B/line (kills same-line RMW serialization)

// ---------------------------------------------------------------------------
// bf16 pack helper (RNE)
// ---------------------------------------------------------------------------
__device__ __forceinline__ unsigned pack_bf2(float x, float y) {
    union { float f; unsigned u; } a, b;
    a.f = x; b.f = y;
    unsigned ra = a.u + 0x7FFFu + ((a.u >> 16) & 1u);
    unsigned rb = b.u + 0x7FFFu + ((b.u >> 16) & 1u);
    return (ra >> 16) | (rb & 0xFFFF0000u);
}

// ---------------------------------------------------------------------------
// seed_mask dtype normalization (verified R1-R3).
// ---------------------------------------------------------------------------
__global__ void mask_norm_kernel(const unsigned char* __restrict__ raw,
                                 int* __restrict__ outMask) {
    __shared__ int s_ni, s_nf;
    int t = threadIdx.x;
    if (t == 0) { s_ni = 0; s_nf = 0; }
    __syncthreads();
    const unsigned int* u32 = (const unsigned int*)raw;
    int not_int = 0, not_flt = 0;
    for (int i = t; i < 512; i += blockDim.x) {
        unsigned int g = u32[i];
        if (g != 0u && g != 1u) not_int = 1;
        if (g != 0u && g != 0x3F800000u) not_flt = 1;
    }
    if (not_int) atomicOr(&s_ni, 1);
    if (not_flt) atomicOr(&s_nf, 1);
    __syncthreads();
    int mode = (!s_ni) ? 0 : ((!s_nf) ? 1 : 2);
    for (int i = t; i < BATCH * MAXSEED; i += blockDim.x) {
        int v;
        if (mode == 0)      v = ((const int*)raw)[i] != 0;
        else if (mode == 1) v = (((const float*)raw)[i] != 0.0f);
        else                v = raw[i] != 0;
        outMask[i] = v;
    }
}

// ---------------------------------------------------------------------------
// Histograms: 4x unrolled int4 loads, 4 independent atomic chains per thread.
// ---------------------------------------------------------------------------
__global__ __launch_bounds__(256) void hist_kernel(
    const int* __restrict__ eidx, int E,
    int* __restrict__ cntS, int* __restrict__ cntD)
{
    const int t = blockIdx.x * blockDim.x + threadIdx.x;
    const int e0 = t * 4;
    if (((E & 3) == 0) && e0 + 3 < E) {
        int4 s4 = *(const int4*)(eidx + e0);
        int4 d4 = *(const int4*)(eidx + E + e0);
        atomicAdd(&cntS[s4.x], 1); atomicAdd(&cntS[s4.y], 1);
        atomicAdd(&cntS[s4.z], 1); atomicAdd(&cntS[s4.w], 1);
        atomicAdd(&cntD[d4.x], 1); atomicAdd(&cntD[d4.y], 1);
        atomicAdd(&cntD[d4.z], 1); atomicAdd(&cntD[d4.w], 1);
    } else {
        for (int e = e0; e < E && e < e0 + 4; ++e) {
            atomicAdd(&cntS[eidx[e]], 1);
            atomicAdd(&cntD[eidx[e + E]], 1);
        }
    }
}

// Exclusive scan: compact cnt -> compact row_ptr + PADDED ofs (stride OPAD).
// blockIdx 0 = src histogram, blockIdx 1 = dst histogram.
__global__ __launch_bounds__(1024) void scan2_kernel(
    const int* __restrict__ cntS, int* __restrict__ rpS, int* __restrict__ ofS,
    const int* __restrict__ cntD, int* __restrict__ rpD, int* __restrict__ ofD)
{
    const int* cnt = blockIdx.x ? cntD : cntS;
    int* row_ptr   = blockIdx.x ? rpD : rpS;
    int* ofs       = blockIdx.x ? ofD : ofS;
    __shared__ int s[1024];
    const int t = threadIdx.x;
    const int CH = 63;
    const int base = t * CH;
    int sum = 0;
    for (int j = 0; j < CH; ++j) { int p = base + j; if (p < N_ENT) sum += cnt[p]; }
    s[t] = sum;
    for (int off = 1; off < 1024; off <<= 1) {
        __syncthreads();
        int x = (t >= off) ? s[t - off] : 0;
        __syncthreads();
        s[t] += x;
    }
    __syncthreads();
    int run = s[t] - sum;
    for (int j = 0; j < CH; ++j) {
        int p = base + j;
        if (p < N_ENT) { row_ptr[p] = run; ofs[(size_t)p * OPAD] = run; run += cnt[p]; }
    }
    if (t == 1023) row_ptr[N_ENT] = s[1023];
}

// Src-order scatter only: ONE atomic per edge (padded counters), payload
// (dst<<6)|rel. 4x unrolled int4 loads.
__global__ __launch_bounds__(256) void scatS_kernel(
    const int* __restrict__ eidx, const int* __restrict__ etype, int E,
    int* __restrict__ ofsS, unsigned* __restrict__ srcSorted)
{
    const int t = blockIdx.x * blockDim.x + threadIdx.x;
    const int e0 = t * 4;
    if (((E & 3) == 0) && e0 + 3 < E) {
        int4 s4 = *(const int4*)(eidx + e0);
        int4 d4 = *(const int4*)(eidx + E + e0);
        int4 r4 = *(const int4*)(etype + e0);
        int p0 = atomicAdd(&ofsS[(size_t)s4.x * OPAD], 1);
        int p1 = atomicAdd(&ofsS[(size_t)s4.y * OPAD], 1);
        int p2 = atomicAdd(&ofsS[(size_t)s4.z * OPAD], 1);
        int p3 = atomicAdd(&ofsS[(size_t)s4.w * OPAD], 1);
        srcSorted[p0] = ((unsigned)d4.x << 6) | (unsigned)r4.x;
        srcSorted[p1] = ((unsigned)d4.y << 6) | (unsigned)r4.y;
        srcSorted[p2] = ((unsigned)d4.z << 6) | (unsigned)r4.z;
        srcSorted[p3] = ((unsigned)d4.w << 6) | (unsigned)r4.w;
    } else {
        for (int e = e0; e < E && e < e0 + 4; ++e) {
            int p = atomicAdd(&ofsS[(size_t)eidx[e] * OPAD], 1);
            srcSorted[p] = ((unsigned)eidx[e + E] << 6) | (unsigned)etype[e];
        }
    }
}

// ---------------------------------------------------------------------------
// Plan A msg: per-src register-cached basis; dst-rank claimed here via
// lane-batched atomics (lanes 0..3 issue 4 edges' atomics in one VMEM instr).
// bf16x2 messages written non-temporally to dst-rank slots. One wave per src.
// ---------------------------------------------------------------------------
__global__ __launch_bounds__(256) void msg_kernel(
    const float* __restrict__ basis, const float* __restrict__ att,
    const int* __restrict__ row_ptrS, const unsigned* __restrict__ srcSorted,
    int* __restrict__ ofsD, unsigned* __restrict__ msg)
{
    __shared__ float att_s[NREL * NB];
    const int t = threadIdx.x;
    for (int i = t; i < NREL * NB; i += 256) att_s[i] = att[i];
    __syncthreads();
    const int lane = t & 63;
    const int s = blockIdx.x * 4 + (t >> 6);
    const int r0 = row_ptrS[s], r1 = row_ptrS[s + 1];
    if (r0 == r1) return;
    float2 B[NB];
#pragma unroll
    for (int b = 0; b < NB; ++b)
        B[b] = ((const float2*)(basis + ((size_t)b * N_ENT + s) * DIM))[lane];
    for (int i = r0; i < r1; i += 4) {
        const int m = min(4, r1 - i);
        unsigned pk_l = (lane < m) ? srcSorted[i + lane] : 0u;
        int q_l = 0;
        if (lane < m) q_l = atomicAdd(&ofsD[(size_t)(pk_l >> 6) * OPAD], 1);
        for (int j = 0; j < m; ++j) {
            unsigned pk = (unsigned)__shfl((int)pk_l, j, 64);
            int q = __shfl(q_l, j, 64);
            const float* __restrict__ c = att_s + (pk & 63u) * NB;
            float mx = 0.f, my = 0.f;
#pragma unroll
            for (int b = 0; b < NB; ++b) { mx += c[b] * B[b].x; my += c[b] * B[b].y; }
            __builtin_nontemporal_store(pack_bf2(mx, my), msg + (size_t)q * 64 + lane);
        }
    }
}

// Segmented reduce over dst-rank bf16 messages; writes nodes once (+root+bias).
__global__ __launch_bounds__(256) void reduce_kernel(
    const unsigned* __restrict__ msg, const int* __restrict__ row_ptrD,
    const float* __restrict__ root, const float* __restrict__ rbias,
    float* __restrict__ nodes)
{
    const int t = threadIdx.x;
    const int lane = t & 63;
    const int d = blockIdx.x * 4 + (t >> 6);
    const int r0 = row_ptrD[d], r1 = row_ptrD[d + 1];
    float2 acc = ((const float2*)(root + (size_t)d * DIM))[lane];
    acc.x += rbias[lane * 2];
    acc.y += rbias[lane * 2 + 1];
    for (int i = r0; i < r1; ++i) {
        unsigned u = __builtin_nontemporal_load(msg + (size_t)i * 64 + lane);
        acc.x += __uint_as_float(u << 16);
        acc.y += __uint_as_float(u & 0xFFFF0000u);
    }
    ((float2*)(nodes + (size_t)d * DIM))[lane] = acc;
}

// ---------------------------------------------------------------------------
// Plan D fallback (small ws): src-sorted + register basis + fp32 atomics.
// Payload (dst<<6)|rel matches scatS.
// ---------------------------------------------------------------------------
__global__ __launch_bounds__(256) void edge_atomic_kernel(
    const float* __restrict__ basis, const float* __restrict__ att,
    const int* __restrict__ row_ptrS, const unsigned* __restrict__ srcSorted,
    float* __restrict__ nodes)
{
    __shared__ float att_s[NREL * NB];
    const int t = threadIdx.x;
    for (int i = t; i < NREL * NB; i += 256) att_s[i] = att[i];
    __syncthreads();
    const int lane = t & 63;
    const int s = blockIdx.x * 4 + (t >> 6);
    const int r0 = row_ptrS[s], r1 = row_ptrS[s + 1];
    if (r0 == r1) return;
    float2 B[NB];
#pragma unroll
    for (int b = 0; b < NB; ++b)
        B[b] = ((const float2*)(basis + ((size_t)b * N_ENT + s) * DIM))[lane];
    for (int i = r0; i < r1; ++i) {
        unsigned pk = srcSorted[i];
        const float* __restrict__ c = att_s + (pk & 63u) * NB;
        int d = (int)(pk >> 6);
        float mx = 0.f, my = 0.f;
#pragma unroll
        for (int b = 0; b < NB; ++b) { mx += c[b] * B[b].x; my += c[b] * B[b].y; }
        float* dp = nodes + (size_t)d * DIM + lane * 2;
        unsafeAtomicAdd(dp, mx);
        unsafeAtomicAdd(dp + 1, my);
    }
}

__global__ __launch_bounds__(256) void finalize_nodes(
    float* __restrict__ nodes, const float* __restrict__ root,
    const float* __restrict__ bias, int total)
{
    int i = blockIdx.x * blockDim.x + threadIdx.x;
    if (i < total) nodes[i] = nodes[i] + root[i] + bias[i & (DIM - 1)];
}

// ---------------------------------------------------------------------------
// Attention pooling (verified R1-R3).
// ---------------------------------------------------------------------------
__global__ __launch_bounds__(128) void attn_kernel(
    const float* __restrict__ nodes, const float* __restrict__ A,
    const float* __restrict__ bvec, const int* __restrict__ seed_idx,
    const int* __restrict__ maskN, float* __restrict__ u)
{
    __shared__ float A_s[DIM * DIM];
    __shared__ float h_s[MAXSEED * DIM];
    __shared__ float ev[MAXSEED];
    __shared__ float aw[MAXSEED];
    __shared__ float red[2];
    const int b = blockIdx.x;
    const int t = threadIdx.x;

    for (int i = t; i < DIM * DIM; i += 128) A_s[i] = A[i];
    for (int l = 0; l < MAXSEED; ++l) {
        int idx = seed_idx[b * MAXSEED + l];
        h_s[l * DIM + t] = nodes[(size_t)idx * DIM + t];
    }
    __syncthreads();

    const float bv = bvec[t];
    for (int l = 0; l < MAXSEED; ++l) {
        float s = 0.f;
#pragma unroll 8
        for (int d1 = 0; d1 < DIM; ++d1) s += h_s[l * DIM + d1] * A_s[d1 * DIM + t];
        float val = tanhf(s) * bv;
#pragma unroll
        for (int off = 32; off > 0; off >>= 1) val += __shfl_down(val, off, 64);
        if ((t & 63) == 0) red[t >> 6] = val;
        __syncthreads();
        if (t == 0) ev[l] = red[0] + red[1];
        __syncthreads();
    }

    if (t == 0) {
        float mx = -1e30f;
        for (int l = 0; l < MAXSEED; ++l)
            if (maskN[b * MAXSEED + l]) mx = fmaxf(mx, ev[l]);
        float den = 0.f;
        for (int l = 0; l < MAXSEED; ++l) {
            float w = maskN[b * MAXSEED + l] ? expf(ev[l] - mx) : 0.f;
            aw[l] = w;
            den += w;
        }
        float inv = 1.f / den;
        for (int l = 0; l < MAXSEED; ++l) aw[l] *= inv;
    }
    __syncthreads();

    float s = 0.f;
    for (int l = 0; l < MAXSEED; ++l) s += aw[l] * h_s[l * DIM + t];
    u[b * DIM + t] = s;
}

// ---------------------------------------------------------------------------
// Scores: lane streams its node row from global, u tile in LDS, acc[16] VGPRs.
// ---------------------------------------------------------------------------
__global__ __launch_bounds__(256) void scores_kernel(
    const float* __restrict__ nodes, const float* __restrict__ u,
    const float* __restrict__ obias, float* __restrict__ out)
{
    __shared__ float u_s[BATCH * DIM];
    const int t = threadIdx.x;
    const int n0 = blockIdx.x * 64;
    for (int i = t; i < BATCH * DIM; i += 256) u_s[i] = u[i];
    __syncthreads();
    const int nl = t & 63, bg = t >> 6;
    const int n = n0 + nl;
    const int nc = n < N_ENT ? n : N_ENT - 1;
    const float4* __restrict__ nrow = (const float4*)(nodes + (size_t)nc * DIM);
    float acc[16];
#pragma unroll
    for (int bi = 0; bi < 16; ++bi) acc[bi] = 0.f;
    for (int dc = 0; dc < DIM / 4; ++dc) {
        const float4 nr = nrow[dc];
#pragma unroll
        for (int bi = 0; bi < 16; ++bi) {
            const float4 uu = *(const float4*)(u_s + (bg * 16 + bi) * DIM + dc * 4);
            acc[bi] += nr.x * uu.x + nr.y * uu.y + nr.z * uu.z + nr.w * uu.w;
        }
    }
    if (n < N_ENT) {
        const float ob = obias[n];
#pragma unroll
        for (int bi = 0; bi < 16; ++bi)
            out[(size_t)(bg * 16 + bi) * N_ENT + n] = acc[bi] + ob;
    }
}

// ---------------------------------------------------------------------------
// Two-stage logsumexp.
// ---------------------------------------------------------------------------
#define LSE_CH 8
__global__ __launch_bounds__(256) void lse1_kernel(
    const float* __restrict__ scores, float2* __restrict__ pls)
{
    const int b = blockIdx.x >> 3, c = blockIdx.x & 7;
    const int t = threadIdx.x;
    const int CH = (N_ENT + LSE_CH - 1) / LSE_CH;
    const int i0 = c * CH, i1 = min(N_ENT, i0 + CH);
    const float* __restrict__ row = scores + (size_t)b * N_ENT;
    __shared__ float red[4], red2[4];
    float mx = -1e30f;
    for (int i = i0 + t; i < i1; i += 256) mx = fmaxf(mx, row[i]);
#pragma unroll
    for (int off = 32; off > 0; off >>= 1) mx = fmaxf(mx, __shfl_down(mx, off, 64));
    if ((t & 63) == 0) red[t >> 6] = mx;
    __syncthreads();
    const float m4 = fmaxf(fmaxf(red[0], red[1]), fmaxf(red[2], red[3]));
    float ss = 0.f;
    for (int i = i0 + t; i < i1; i += 256) ss += expf(row[i] - m4);
#pragma unroll
    for (int off = 32; off > 0; off >>= 1) ss += __shfl_down(ss, off, 64);
    if ((t & 63) == 0) red2[t >> 6] = ss;
    __syncthreads();
    if (t == 0) pls[blockIdx.x] = make_float2(m4, red2[0] + red2[1] + red2[2] + red2[3]);
}

__global__ void lse2_kernel(const float2* __restrict__ pls, float* __restrict__ lse)
{
    const int b = threadIdx.x;
    if (b < BATCH) {
        float M = -1e30f;
        for (int c = 0; c < LSE_CH; ++c) M = fmaxf(M, pls[b * LSE_CH + c].x);
        float S = 0.f;
        for (int c = 0; c < LSE_CH; ++c) {
            float2 p = pls[b * LSE_CH + c];
            S += p.y * expf(p.x - M);
        }
        lse[b] = M + logf(S);
    }
}

__global__ void loss_kernel(const float* __restrict__ scores,
                            const float* __restrict__ lse,
                            const int* __restrict__ labels,
                            float* __restrict__ out_loss)
{
    const int t = threadIdx.x;
    float v = 0.f;
    if (t < BATCH) {
        int lab = labels[t];
        v = lse[t] - scores[(size_t)t * N_ENT + lab];
    }
#pragma unroll
    for (int off = 32; off > 0; off >>= 1) v += __shfl_down(v, off, 64);
    if (t == 0) out_loss[0] = v * (1.0f / BATCH);
}

extern "C" void kernel_launch(void* const* d_in, const int* in_sizes, int n_in,
                              void* d_out, int out_size, void* d_ws, size_t ws_size,
                              hipStream_t stream) {
    const float* basis = (const float*)d_in[0];
    const float* att   = (const float*)d_in[1];
    const float* root  = (const float*)d_in[2];
    const float* rbias = (const float*)d_in[3];
    const float* attnA = (const float*)d_in[4];
    const float* attnB = (const float*)d_in[5];
    const float* obias = (const float*)d_in[6];
    const int* eindex  = (const int*)d_in[7];
    const int* etype   = (const int*)d_in[8];
    const int* sidx    = (const int*)d_in[9];
    const unsigned char* smask = (const unsigned char*)d_in[10];
    const int* labels  = (const int*)d_in[11];
    const int E = in_sizes[8];
    float* out = (float*)d_out;

    // ---- workspace layout ----
    auto alignup = [](size_t x) { return (x + 511) & ~(size_t)511; };
    char* p = (char*)d_ws;
    float* nodes = (float*)p;      p += alignup((size_t)N_ENT * DIM * 4);
    float* u     = (float*)p;      p += alignup((size_t)BATCH * DIM * 4);
    float* lse   = (float*)p;      p += alignup(BATCH * 4);
    float2* pls  = (float2*)p;     p += alignup(BATCH * LSE_CH * 8);
    int* maskN   = (int*)p;        p += alignup(BATCH * MAXSEED * 4);
    int* cntS    = (int*)p;
    int* cntD    = cntS + N_ENT;   p += alignup((size_t)2 * N_ENT * 4);
    int* row_ptrS= (int*)p;        p += alignup((size_t)(N_ENT + 1) * 4);
    int* row_ptrD= (int*)p;        p += alignup((size_t)(N_ENT + 1) * 4);
    int* ofsS    = (int*)p;        p += alignup((size_t)N_ENT * OPAD * 4);  // 64B/counter
    int* ofsD    = (int*)p;        p += alignup((size_t)N_ENT * OPAD * 4);
    unsigned* srcSorted = (unsigned*)p; p += alignup((size_t)E * 4);
    unsigned* msg = (unsigned*)p;  p += alignup((size_t)E * 64 * 4);  // bf16x2 per lane
    const bool planA = ((size_t)(p - (char*)d_ws) <= ws_size);

    const int gridE4 = ((E + 3) / 4 + 255) / 256;

    mask_norm_kernel<<<1, 256, 0, stream>>>(smask, maskN);
    hipMemsetAsync(cntS, 0, (size_t)2 * N_ENT * 4, stream);
    hist_kernel<<<gridE4, 256, 0, stream>>>(eindex, E, cntS, cntD);
    scan2_kernel<<<2, 1024, 0, stream>>>(cntS, row_ptrS, ofsS, cntD, row_ptrD, ofsD);
    scatS_kernel<<<gridE4, 256, 0, stream>>>(eindex, etype, E, ofsS, srcSorted);

    if (planA) {
        msg_kernel<<<N_ENT / 4, 256, 0, stream>>>(basis, att, row_ptrS, srcSorted, ofsD, msg);
        reduce_kernel<<<N_ENT / 4, 256, 0, stream>>>(msg, row_ptrD, root, rbias, nodes);
    } else {
        hipMemsetAsync(nodes, 0, (size_t)N_ENT * DIM * 4, stream);
        edge_atomic_kernel<<<N_ENT / 4, 256, 0, stream>>>(basis, att, row_ptrS, srcSorted, nodes);
        finalize_nodes<<<((N_ENT * DIM) + 255) / 256, 256, 0, stream>>>(nodes, root, rbias, N_ENT * DIM);
    }

    attn_kernel<<<BATCH, 128, 0, stream>>>(nodes, attnA, attnB, sidx, maskN, u);
    scores_kernel<<<(N_ENT + 63) / 64, 256, 0, stream>>>(nodes, u, obias, out);
    lse1_kernel<<<BATCH * LSE_CH, 256, 0, stream>>>(out, pls);
    lse2_kernel<<<1, 64, 0, stream>>>(pls, lse);
    loss_kernel<<<1, 64, 0, stream>>>(out, lse, labels, out + (size_t)BATCH * N_ENT);
}

// Round 5
// 968.139 us; speedup vs baseline: 1.7599x; 1.0750x over previous
//
#include <hip/hip_runtime.h>
#include <hip/hip_bf16.h>

#define N_ENT 64368
#define DIM 128
#define NB 8
#define NREL 40
#define BATCH 64
#define MAXSEED 32
#define OPAD 16   // ints per padded atomic counter = 64 B/line
#define NBLK ((N_ENT + 63) / 64)   // 1006 score tiles

// fp8 message path (OCP e4m3 on gfx950); falls back to bf16 if builtin absent.
#if defined(__has_builtin)
#if __has_builtin(__builtin_amdgcn_cvt_pk_fp8_f32) && __has_builtin(__builtin_amdgcn_cvt_pk_f32_fp8)
#define USE_FP8 1
#endif
#endif
#ifndef USE_FP8
#define USE_FP8 0
#endif

#define MSG_SCALE 128.0f        // keeps |msg| (~0.006 sigma) out of e4m3 denormals
#define MSG_INV_SCALE (1.0f / 128.0f)

typedef float v2f __attribute__((ext_vector_type(2)));

__device__ __forceinline__ unsigned pack_bf2(float x, float y) {
    union { float f; unsigned u; } a, b;
    a.f = x; b.f = y;
    unsigned ra = a.u + 0x7FFFu + ((a.u >> 16) & 1u);
    unsigned rb = b.u + 0x7FFFu + ((b.u >> 16) & 1u);
    return (ra >> 16) | (rb & 0xFFFF0000u);
}

// ---------------------------------------------------------------------------
// Histograms: 4x unrolled int4 loads, independent atomic chains.
// ---------------------------------------------------------------------------
__global__ __launch_bounds__(256) void hist_kernel(
    const int* __restrict__ eidx, int E,
    int* __restrict__ cntS, int* __restrict__ cntD)
{
    const int t = blockIdx.x * blockDim.x + threadIdx.x;
    const int e0 = t * 4;
    if (((E & 3) == 0) && e0 + 3 < E) {
        int4 s4 = *(const int4*)(eidx + e0);
        int4 d4 = *(const int4*)(eidx + E + e0);
        atomicAdd(&cntS[s4.x], 1); atomicAdd(&cntS[s4.y], 1);
        atomicAdd(&cntS[s4.z], 1); atomicAdd(&cntS[s4.w], 1);
        atomicAdd(&cntD[d4.x], 1); atomicAdd(&cntD[d4.y], 1);
        atomicAdd(&cntD[d4.z], 1); atomicAdd(&cntD[d4.w], 1);
    } else {
        for (int e = e0; e < E && e < e0 + 4; ++e) {
            atomicAdd(&cntS[eidx[e]], 1);
            atomicAdd(&cntD[eidx[e + E]], 1);
        }
    }
}

// Exclusive scan: compact cnt -> compact row_ptr + PADDED ofs (stride OPAD).
__global__ __launch_bounds__(1024) void scan2_kernel(
    const int* __restrict__ cntS, int* __restrict__ rpS, int* __restrict__ ofS,
    const int* __restrict__ cntD, int* __restrict__ rpD, int* __restrict__ ofD)
{
    const int* cnt = blockIdx.x ? cntD : cntS;
    int* row_ptr   = blockIdx.x ? rpD : rpS;
    int* ofs       = blockIdx.x ? ofD : ofS;
    __shared__ int s[1024];
    const int t = threadIdx.x;
    const int CH = 63;
    const int base = t * CH;
    int sum = 0;
    for (int j = 0; j < CH; ++j) { int p = base + j; if (p < N_ENT) sum += cnt[p]; }
    s[t] = sum;
    for (int off = 1; off < 1024; off <<= 1) {
        __syncthreads();
        int x = (t >= off) ? s[t - off] : 0;
        __syncthreads();
        s[t] += x;
    }
    __syncthreads();
    int run = s[t] - sum;
    for (int j = 0; j < CH; ++j) {
        int p = base + j;
        if (p < N_ENT) { row_ptr[p] = run; ofs[(size_t)p * OPAD] = run; run += cnt[p]; }
    }
    if (t == 1023) row_ptr[N_ENT] = s[1023];
}

// Src-order scatter: ONE atomic per edge (padded counters), payload (dst<<6)|rel.
__global__ __launch_bounds__(256) void scatS_kernel(
    const int* __restrict__ eidx, const int* __restrict__ etype, int E,
    int* __restrict__ ofsS, unsigned* __restrict__ srcSorted)
{
    const int t = blockIdx.x * blockDim.x + threadIdx.x;
    const int e0 = t * 4;
    if (((E & 3) == 0) && e0 + 3 < E) {
        int4 s4 = *(const int4*)(eidx + e0);
        int4 d4 = *(const int4*)(eidx + E + e0);
        int4 r4 = *(const int4*)(etype + e0);
        int p0 = atomicAdd(&ofsS[(size_t)s4.x * OPAD], 1);
        int p1 = atomicAdd(&ofsS[(size_t)s4.y * OPAD], 1);
        int p2 = atomicAdd(&ofsS[(size_t)s4.z * OPAD], 1);
        int p3 = atomicAdd(&ofsS[(size_t)s4.w * OPAD], 1);
        srcSorted[p0] = ((unsigned)d4.x << 6) | (unsigned)r4.x;
        srcSorted[p1] = ((unsigned)d4.y << 6) | (unsigned)r4.y;
        srcSorted[p2] = ((unsigned)d4.z << 6) | (unsigned)r4.z;
        srcSorted[p3] = ((unsigned)d4.w << 6) | (unsigned)r4.w;
    } else {
        for (int e = e0; e < E && e < e0 + 4; ++e) {
            int p = atomicAdd(&ofsS[(size_t)eidx[e] * OPAD], 1);
            srcSorted[p] = ((unsigned)eidx[e + E] << 6) | (unsigned)etype[e];
        }
    }
}

// ---------------------------------------------------------------------------
// msg: per-src register basis; dst-rank claimed via lane-batched atomics;
// fp8x2 (or bf16x2) messages written non-temporally. One wave per src.
// ---------------------------------------------------------------------------
__global__ __launch_bounds__(256) void msg_kernel(
    const float* __restrict__ basis, const float* __restrict__ att,
    const int* __restrict__ row_ptrS, const unsigned* __restrict__ srcSorted,
    int* __restrict__ ofsD, void* __restrict__ msgv)
{
    __shared__ float att_s[NREL * NB];
    const int t = threadIdx.x;
    const float ascale = USE_FP8 ? MSG_SCALE : 1.0f;
    for (int i = t; i < NREL * NB; i += 256) att_s[i] = att[i] * ascale;
    __syncthreads();
    const int lane = t & 63;
    const int s = blockIdx.x * 4 + (t >> 6);
    const int r0 = row_ptrS[s], r1 = row_ptrS[s + 1];
    if (r0 == r1) return;
    float2 B[NB];
#pragma unroll
    for (int b = 0; b < NB; ++b)
        B[b] = ((const float2*)(basis + ((size_t)b * N_ENT + s) * DIM))[lane];
#if USE_FP8
    unsigned short* __restrict__ msg8 = (unsigned short*)msgv;
#else
    unsigned* __restrict__ msg = (unsigned*)msgv;
#endif
    for (int i = r0; i < r1; i += 4) {
        const int m = min(4, r1 - i);
        unsigned pk_l = (lane < m) ? srcSorted[i + lane] : 0u;
        int q_l = 0;
        if (lane < m) q_l = atomicAdd(&ofsD[(size_t)(pk_l >> 6) * OPAD], 1);
        for (int j = 0; j < m; ++j) {
            unsigned pk = (unsigned)__shfl((int)pk_l, j, 64);
            int q = __shfl(q_l, j, 64);
            const float* __restrict__ c = att_s + (pk & 63u) * NB;
            float mx = 0.f, my = 0.f;
#pragma unroll
            for (int b = 0; b < NB; ++b) { mx += c[b] * B[b].x; my += c[b] * B[b].y; }
#if USE_FP8
            int p8 = __builtin_amdgcn_cvt_pk_fp8_f32(mx, my, 0, false);
            __builtin_nontemporal_store((unsigned short)p8,
                                        msg8 + (size_t)q * 64 + lane);
#else
            __builtin_nontemporal_store(pack_bf2(mx, my),
                                        (unsigned*)msg + (size_t)q * 64 + lane);
#endif
        }
    }
}

// Segmented reduce, 4-way unrolled with independent accumulators.
__global__ __launch_bounds__(256) void reduce_kernel(
    const void* __restrict__ msgv, const int* __restrict__ row_ptrD,
    const float* __restrict__ root, const float* __restrict__ rbias,
    float* __restrict__ nodes)
{
    const int t = threadIdx.x;
    const int lane = t & 63;
    const int d = blockIdx.x * 4 + (t >> 6);
    const int r0 = row_ptrD[d], r1 = row_ptrD[d + 1];
    float ax0 = 0.f, ay0 = 0.f, ax1 = 0.f, ay1 = 0.f;
    float ax2 = 0.f, ay2 = 0.f, ax3 = 0.f, ay3 = 0.f;
    int i = r0;
#if USE_FP8
    const unsigned short* __restrict__ msg8 = (const unsigned short*)msgv;
    for (; i + 3 < r1; i += 4) {
        unsigned short v0 = __builtin_nontemporal_load(msg8 + (size_t)(i + 0) * 64 + lane);
        unsigned short v1 = __builtin_nontemporal_load(msg8 + (size_t)(i + 1) * 64 + lane);
        unsigned short v2 = __builtin_nontemporal_load(msg8 + (size_t)(i + 2) * 64 + lane);
        unsigned short v3 = __builtin_nontemporal_load(msg8 + (size_t)(i + 3) * 64 + lane);
        v2f f0 = __builtin_amdgcn_cvt_pk_f32_fp8((int)v0, false);
        v2f f1 = __builtin_amdgcn_cvt_pk_f32_fp8((int)v1, false);
        v2f f2 = __builtin_amdgcn_cvt_pk_f32_fp8((int)v2, false);
        v2f f3 = __builtin_amdgcn_cvt_pk_f32_fp8((int)v3, false);
        ax0 += f0.x; ay0 += f0.y; ax1 += f1.x; ay1 += f1.y;
        ax2 += f2.x; ay2 += f2.y; ax3 += f3.x; ay3 += f3.y;
    }
    for (; i < r1; ++i) {
        unsigned short v = __builtin_nontemporal_load(msg8 + (size_t)i * 64 + lane);
        v2f f = __builtin_amdgcn_cvt_pk_f32_fp8((int)v, false);
        ax0 += f.x; ay0 += f.y;
    }
#else
    const unsigned* __restrict__ msg = (const unsigned*)msgv;
    for (; i + 3 < r1; i += 4) {
        unsigned u0 = __builtin_nontemporal_load(msg + (size_t)(i + 0) * 64 + lane);
        unsigned u1 = __builtin_nontemporal_load(msg + (size_t)(i + 1) * 64 + lane);
        unsigned u2 = __builtin_nontemporal_load(msg + (size_t)(i + 2) * 64 + lane);
        unsigned u3 = __builtin_nontemporal_load(msg + (size_t)(i + 3) * 64 + lane);
        ax0 += __uint_as_float(u0 << 16); ay0 += __uint_as_float(u0 & 0xFFFF0000u);
        ax1 += __uint_as_float(u1 << 16); ay1 += __uint_as_float(u1 & 0xFFFF0000u);
        ax2 += __uint_as_float(u2 << 16); ay2 += __uint_as_float(u2 & 0xFFFF0000u);
        ax3 += __uint_as_float(u3 << 16); ay3 += __uint_as_float(u3 & 0xFFFF0000u);
    }
    for (; i < r1; ++i) {
        unsigned u = __builtin_nontemporal_load(msg + (size_t)i * 64 + lane);
        ax0 += __uint_as_float(u << 16); ay0 += __uint_as_float(u & 0xFFFF0000u);
    }
#endif
    const float unscale = USE_FP8 ? MSG_INV_SCALE : 1.0f;
    float2 acc = ((const float2*)(root + (size_t)d * DIM))[lane];
    acc.x += rbias[lane * 2]     + ((ax0 + ax1) + (ax2 + ax3)) * unscale;
    acc.y += rbias[lane * 2 + 1] + ((ay0 + ay1) + (ay2 + ay3)) * unscale;
    ((float2*)(nodes + (size_t)d * DIM))[lane] = acc;
}

// ---------------------------------------------------------------------------
// Plan D fallback (small ws): src-sorted + register basis + fp32 atomics.
// ---------------------------------------------------------------------------
__global__ __launch_bounds__(256) void edge_atomic_kernel(
    const float* __restrict__ basis, const float* __restrict__ att,
    const int* __restrict__ row_ptrS, const unsigned* __restrict__ srcSorted,
    float* __restrict__ nodes)
{
    __shared__ float att_s[NREL * NB];
    const int t = threadIdx.x;
    for (int i = t; i < NREL * NB; i += 256) att_s[i] = att[i];
    __syncthreads();
    const int lane = t & 63;
    const int s = blockIdx.x * 4 + (t >> 6);
    const int r0 = row_ptrS[s], r1 = row_ptrS[s + 1];
    if (r0 == r1) return;
    float2 B[NB];
#pragma unroll
    for (int b = 0; b < NB; ++b)
        B[b] = ((const float2*)(basis + ((size_t)b * N_ENT + s) * DIM))[lane];
    for (int i = r0; i < r1; ++i) {
        unsigned pk = srcSorted[i];
        const float* __restrict__ c = att_s + (pk & 63u) * NB;
        int d = (int)(pk >> 6);
        float mx = 0.f, my = 0.f;
#pragma unroll
        for (int b = 0; b < NB; ++b) { mx += c[b] * B[b].x; my += c[b] * B[b].y; }
        float* dp = nodes + (size_t)d * DIM + lane * 2;
        unsafeAtomicAdd(dp, mx);
        unsafeAtomicAdd(dp + 1, my);
    }
}

__global__ __launch_bounds__(256) void finalize_nodes(
    float* __restrict__ nodes, const float* __restrict__ root,
    const float* __restrict__ bias, int total)
{
    int i = blockIdx.x * blockDim.x + threadIdx.x;
    if (i < total) nodes[i] = nodes[i] + root[i] + bias[i & (DIM - 1)];
}

// ---------------------------------------------------------------------------
// Attention pooling with inlined seed_mask normalization (mask_norm folded in).
// ---------------------------------------------------------------------------
__global__ __launch_bounds__(128) void attn_kernel(
    const float* __restrict__ nodes, const float* __restrict__ A,
    const float* __restrict__ bvec, const int* __restrict__ seed_idx,
    const unsigned char* __restrict__ rawmask, float* __restrict__ u)
{
    __shared__ float A_s[DIM * DIM];
    __shared__ float h_s[MAXSEED * DIM];
    __shared__ float ev[MAXSEED];
    __shared__ float aw[MAXSEED];
    __shared__ float red[2];
    __shared__ int m_s[MAXSEED];
    __shared__ int s_ni, s_nf;
    const int b = blockIdx.x;
    const int t = threadIdx.x;

    // --- mask dtype detection (reads only the always-safe first 2048 bytes) ---
    if (t == 0) { s_ni = 0; s_nf = 0; }
    __syncthreads();
    {
        const unsigned int* u32 = (const unsigned int*)rawmask;
        int not_int = 0, not_flt = 0;
        for (int i = t; i < 512; i += 128) {
            unsigned g = u32[i];
            if (g != 0u && g != 1u) not_int = 1;
            if (g != 0u && g != 0x3F800000u) not_flt = 1;
        }
        if (not_int) atomicOr(&s_ni, 1);
        if (not_flt) atomicOr(&s_nf, 1);
    }

    for (int i = t; i < DIM * DIM; i += 128) A_s[i] = A[i];
    for (int l = 0; l < MAXSEED; ++l) {
        int idx = seed_idx[b * MAXSEED + l];
        h_s[l * DIM + t] = nodes[(size_t)idx * DIM + t];
    }
    __syncthreads();
    if (t < MAXSEED) {
        int mode = (!s_ni) ? 0 : ((!s_nf) ? 1 : 2);
        int gi = b * MAXSEED + t;
        int v;
        if (mode == 0)      v = ((const int*)rawmask)[gi] != 0;
        else if (mode == 1) v = (((const float*)rawmask)[gi] != 0.0f);
        else                v = rawmask[gi] != 0;
        m_s[t] = v;
    }
    __syncthreads();

    const float bv = bvec[t];
    for (int l = 0; l < MAXSEED; ++l) {
        float s = 0.f;
#pragma unroll 8
        for (int d1 = 0; d1 < DIM; ++d1) s += h_s[l * DIM + d1] * A_s[d1 * DIM + t];
        float val = tanhf(s) * bv;
#pragma unroll
        for (int off = 32; off > 0; off >>= 1) val += __shfl_down(val, off, 64);
        if ((t & 63) == 0) red[t >> 6] = val;
        __syncthreads();
        if (t == 0) ev[l] = red[0] + red[1];
        __syncthreads();
    }

    if (t == 0) {
        float mx = -1e30f;
        for (int l = 0; l < MAXSEED; ++l)
            if (m_s[l]) mx = fmaxf(mx, ev[l]);
        float den = 0.f;
        for (int l = 0; l < MAXSEED; ++l) {
            float w = m_s[l] ? expf(ev[l] - mx) : 0.f;
            aw[l] = w;
            den += w;
        }
        float inv = 1.f / den;
        for (int l = 0; l < MAXSEED; ++l) aw[l] *= inv;
    }
    __syncthreads();

    float s = 0.f;
    for (int l = 0; l < MAXSEED; ++l) s += aw[l] * h_s[l * DIM + t];
    u[b * DIM + t] = s;
}

// ---------------------------------------------------------------------------
// Scores + fused per-tile logsumexp partials (lse1 eliminated).
// ---------------------------------------------------------------------------
__global__ __launch_bounds__(256) void scores_kernel(
    const float* __restrict__ nodes, const float* __restrict__ u,
    const float* __restrict__ obias, float* __restrict__ out,
    float2* __restrict__ pls)
{
    __shared__ float u_s[BATCH * DIM];
    const int t = threadIdx.x;
    const int n0 = blockIdx.x * 64;
    for (int i = t; i < BATCH * DIM; i += 256) u_s[i] = u[i];
    __syncthreads();
    const int nl = t & 63, bg = t >> 6;
    const int n = n0 + nl;
    const bool valid = (n < N_ENT);
    const int nc = valid ? n : N_ENT - 1;
    const float4* __restrict__ nrow = (const float4*)(nodes + (size_t)nc * DIM);
    float acc[16];
#pragma unroll
    for (int bi = 0; bi < 16; ++bi) acc[bi] = 0.f;
    for (int dc = 0; dc < DIM / 4; ++dc) {
        const float4 nr = nrow[dc];
#pragma unroll
        for (int bi = 0; bi < 16; ++bi) {
            const float4 uu = *(const float4*)(u_s + (bg * 16 + bi) * DIM + dc * 4);
            acc[bi] += nr.x * uu.x + nr.y * uu.y + nr.z * uu.z + nr.w * uu.w;
        }
    }
    const float ob = valid ? obias[n] : 0.f;
#pragma unroll
    for (int bi = 0; bi < 16; ++bi) {
        float v = valid ? acc[bi] + ob : -INFINITY;
        if (valid) out[(size_t)(bg * 16 + bi) * N_ENT + n] = v;
        // wave-wide butterfly max then sum(exp(v-m)) over the 64-entity tile
        float m = v;
#pragma unroll
        for (int mk = 1; mk < 64; mk <<= 1) m = fmaxf(m, __shfl_xor(m, mk, 64));
        float e = valid ? __expf(v - m) : 0.f;
#pragma unroll
        for (int mk = 1; mk < 64; mk <<= 1) e += __shfl_xor(e, mk, 64);
        if (nl == 0)
            pls[(size_t)(bg * 16 + bi) * NBLK + blockIdx.x] = make_float2(m, e);
    }
}

// Combine per-tile partials -> lse[b]. One block per batch row.
__global__ __launch_bounds__(256) void lse2_kernel(
    const float2* __restrict__ pls, float* __restrict__ lse)
{
    __shared__ float red[4], red2[4];
    const int b = blockIdx.x, t = threadIdx.x;
    const float2* __restrict__ row = pls + (size_t)b * NBLK;
    float mx = -1e30f;
    for (int i = t; i < NBLK; i += 256) mx = fmaxf(mx, row[i].x);
#pragma unroll
    for (int off = 32; off > 0; off >>= 1) mx = fmaxf(mx, __shfl_down(mx, off, 64));
    if ((t & 63) == 0) red[t >> 6] = mx;
    __syncthreads();
    const float M = fmaxf(fmaxf(red[0], red[1]), fmaxf(red[2], red[3]));
    float s = 0.f;
    for (int i = t; i < NBLK; i += 256) {
        float2 p = row[i];
        s += p.y * expf(p.x - M);
    }
#pragma unroll
    for (int off = 32; off > 0; off >>= 1) s += __shfl_down(s, off, 64);
    if ((t & 63) == 0) red2[t >> 6] = s;
    __syncthreads();
    if (t == 0) lse[b] = M + logf(red2[0] + red2[1] + red2[2] + red2[3]);
}

__global__ void loss_kernel(const float* __restrict__ scores,
                            const float* __restrict__ lse,
                            const int* __restrict__ labels,
                            float* __restrict__ out_loss)
{
    const int t = threadIdx.x;
    float v = 0.f;
    if (t < BATCH) {
        int lab = labels[t];
        v = lse[t] - scores[(size_t)t * N_ENT + lab];
    }
#pragma unroll
    for (int off = 32; off > 0; off >>= 1) v += __shfl_down(v, off, 64);
    if (t == 0) out_loss[0] = v * (1.0f / BATCH);
}

extern "C" void kernel_launch(void* const* d_in, const int* in_sizes, int n_in,
                              void* d_out, int out_size, void* d_ws, size_t ws_size,
                              hipStream_t stream) {
    const float* basis = (const float*)d_in[0];
    const float* att   = (const float*)d_in[1];
    const float* root  = (const float*)d_in[2];
    const float* rbias = (const float*)d_in[3];
    const float* attnA = (const float*)d_in[4];
    const float* attnB = (const float*)d_in[5];
    const float* obias = (const float*)d_in[6];
    const int* eindex  = (const int*)d_in[7];
    const int* etype   = (const int*)d_in[8];
    const int* sidx    = (const int*)d_in[9];
    const unsigned char* smask = (const unsigned char*)d_in[10];
    const int* labels  = (const int*)d_in[11];
    const int E = in_sizes[8];
    float* out = (float*)d_out;

    // ---- workspace layout ----
    auto alignup = [](size_t x) { return (x + 511) & ~(size_t)511; };
    char* p = (char*)d_ws;
    float* nodes = (float*)p;      p += alignup((size_t)N_ENT * DIM * 4);
    float* u     = (float*)p;      p += alignup((size_t)BATCH * DIM * 4);
    float* lse   = (float*)p;      p += alignup(BATCH * 4);
    float2* pls  = (float2*)p;     p += alignup((size_t)BATCH * NBLK * 8);
    int* cntS    = (int*)p;
    int* cntD    = cntS + N_ENT;   p += alignup((size_t)2 * N_ENT * 4);
    int* row_ptrS= (int*)p;        p += alignup((size_t)(N_ENT + 1) * 4);
    int* row_ptrD= (int*)p;        p += alignup((size_t)(N_ENT + 1) * 4);
    int* ofsS    = (int*)p;        p += alignup((size_t)N_ENT * OPAD * 4);
    int* ofsD    = (int*)p;        p += alignup((size_t)N_ENT * OPAD * 4);
    unsigned* srcSorted = (unsigned*)p; p += alignup((size_t)E * 4);
    void* msg    = (void*)p;       p += alignup((size_t)E * 64 * 4);  // sized for bf16 fallback
    const bool planA = ((size_t)(p - (char*)d_ws) <= ws_size);

    const int gridE4 = ((E + 3) / 4 + 255) / 256;

    hipMemsetAsync(cntS, 0, (size_t)2 * N_ENT * 4, stream);
    hist_kernel<<<gridE4, 256, 0, stream>>>(eindex, E, cntS, cntD);
    scan2_kernel<<<2, 1024, 0, stream>>>(cntS, row_ptrS, ofsS, cntD, row_ptrD, ofsD);
    scatS_kernel<<<gridE4, 256, 0, stream>>>(eindex, etype, E, ofsS, srcSorted);

    if (planA) {
        msg_kernel<<<N_ENT / 4, 256, 0, stream>>>(basis, att, row_ptrS, srcSorted, ofsD, msg);
        reduce_kernel<<<N_ENT / 4, 256, 0, stream>>>(msg, row_ptrD, root, rbias, nodes);
    } else {
        hipMemsetAsync(nodes, 0, (size_t)N_ENT * DIM * 4, stream);
        edge_atomic_kernel<<<N_ENT / 4, 256, 0, stream>>>(basis, att, row_ptrS, srcSorted, nodes);
        finalize_nodes<<<((N_ENT * DIM) + 255) / 256, 256, 0, stream>>>(nodes, root, rbias, N_ENT * DIM);
    }

    attn_kernel<<<BATCH, 128, 0, stream>>>(nodes, attnA, attnB, sidx, smask, u);
    scores_kernel<<<NBLK, 256, 0, stream>>>(nodes, u, obias, out, pls);
    lse2_kernel<<<BATCH, 256, 0, stream>>>(pls, lse);
    loss_kernel<<<1, 64, 0, stream>>>(out, lse, labels, out + (size_t)BATCH * N_ENT);
}